// Round 17
// baseline (156.401 us; speedup 1.0000x reference)
//
#include <hip/hip_runtime.h>

#define COUT 64
#define KNB 27
#define BN_EPS 1e-5f
#define NBANDS 6
#define NGRP 3   // groups (of 16 nodes) per wave per iteration

typedef __attribute__((ext_vector_type(8))) short short8v;  // 8 bf16 (4 VGPRs)
typedef __attribute__((ext_vector_type(4))) float f32x4;

union U4S8 { uint4 u; short8v s; };

// f32 -> bf16, round-to-nearest-even
static __device__ __forceinline__ unsigned f2bf(float f) {
    unsigned u = __float_as_uint(f);
    return (u + 0x7fffu + ((u >> 16) & 1u)) >> 16;
}

// scattered gather direct to LDS: per-lane global src, dest = lbase + lane*4
static __device__ __forceinline__ void glds4(const void* g, void* l) {
    __builtin_amdgcn_global_load_lds(
        (const __attribute__((address_space(1))) void*)g,
        (__attribute__((address_space(3))) void*)l, 4, 0, 0);
}

// ---------------- Kernel 0: pre-convert x rows to packed bf16 ----------------
__global__ __launch_bounds__(256) void xconv_kernel(
    const float4* __restrict__ x, uint2* __restrict__ xb, int n_in)
{
    int i = blockIdx.x * 256 + threadIdx.x;
    if (i >= n_in) return;
    float4 r = x[i];
    uint2 o;
    o.x = f2bf(r.x) | (f2bf(r.y) << 16);
    o.y = f2bf(r.z) | (f2bf(r.w) << 16);
    xb[i] = o;
}

// ---------------- Kernel 1: banded gather-conv, gathers DMA'd to LDS ----------
// R17 targets the combined corner isolated by R14 (3 blk/CU -> 2.98 TB/s read)
// and R15 (NGRP=4 -> 259MB traffic): NGRP=3 at 3 blocks/CU.
//  - B-fragments in VGPRs (proven R3); LDS = xls 48KB only -> 3 blocks/CU.
//  - ia_nxt prefetch dropped to keep VGPR liveness ~130 (launch_bounds(256,3)
//    caps at ~168; R8-R10 showed starvation only when liveness > cap).
//  - counted vmcnt(16) drains bands 0..4, vmcnt(0) final band (R14 proven).
//  - NGRP=3: 25000 groups not divisible -> per-GROUP validity guard on BOTH
//    y-store and BN-stat accumulation (stale xls slots must not enter sums).
__global__ __launch_bounds__(256, 3) void conv_stats_kernel(
    const uint2* __restrict__ xb,      // [N_in] packed bf16 rows (8B)
    const float* __restrict__ w,       // [27][4][64]
    const int*   __restrict__ nidx,    // [N_out][27]
    unsigned short* __restrict__ yb,   // [N_out][64] bf16 (workspace)
    float*       __restrict__ stats,   // [128]: sum[64], sumsq[64]
    int n_out, int band)
{
    const int lane = threadIdx.x & 63;
    const int wid  = threadIdx.x >> 6;
    const int row  = lane & 15;   // A-row (node) / B-col (channel) selector
    const int grp  = lane >> 4;   // k-chunk selector
    const int gwave   = blockIdx.x * 4 + wid;
    const int nwaves  = gridDim.x * 4;
    const int ngroups = (n_out + 15) >> 4;
    const int npairs  = (ngroups + NGRP - 1) / NGRP;
    const int niter   = (npairs + nwaves - 1) / nwaves;   // uniform trip count

    // ---- per-wave gather buffer: [wave][slot][lane] uint, slot = gi*16+kb*4+h*2+w
    __shared__ unsigned xls[4][NGRP * 16][64];   // 48KB

    // ---- B fragments in registers: bfrag[t][kb] (64 VGPRs, compile-time idx) --
    U4S8 bfrag[4][4];
#pragma unroll
    for (int t = 0; t < 4; ++t)
#pragma unroll
        for (int kb = 0; kb < 4; ++kb) {
            const int o = t * 16 + row;
            unsigned e[8];
#pragma unroll
            for (int j = 0; j < 8; ++j) {
                const int k = kb * 32 + grp * 8 + j;
                float v = (k < KNB * 4) ? w[k * COUT + o] : 0.0f;
                e[j] = f2bf(v);
            }
            bfrag[t][kb].u = make_uint4(e[0] | (e[1] << 16), e[2] | (e[3] << 16),
                                        e[4] | (e[5] << 16), e[6] | (e[7] << 16));
        }

    // zero gather buffer once: always-invalid slots (nb>=27) stay 0 forever
#pragma unroll
    for (int s = 0; s < NGRP * 16; ++s) xls[wid][s][lane] = 0u;
    __syncthreads();

    float sum[4]   = {0.f, 0.f, 0.f, 0.f};
    float sumsq[4] = {0.f, 0.f, 0.f, 0.f};

    for (int it = 0; it < niter; ++it) {
        const int p = gwave + it * nwaves;   // may exceed npairs

        // ---- load this iteration's neighbor indices (24 per lane) ----
        int ia[NGRP][4][2];
#pragma unroll
        for (int gi = 0; gi < NGRP; ++gi) {
            const int gg = p * NGRP + gi;
            const int nodeg = (gg << 4) + row;
            const bool vn = (gg < ngroups);
#pragma unroll
            for (int kb = 0; kb < 4; ++kb)
#pragma unroll
                for (int h = 0; h < 2; ++h) {
                    const int nb = kb * 8 + grp * 2 + h;
                    ia[gi][kb][h] = (vn && nb < KNB) ? nidx[nodeg * KNB + nb] : -1;
                }
        }

        // ---- banded gather sweep: DMA to LDS, counted drains ----
#pragma unroll
        for (int b = 0; b < NBANDS; ++b) {
            const int lo = b * band;
#pragma unroll
            for (int gi = 0; gi < NGRP; ++gi)
#pragma unroll
                for (int kb = 0; kb < 4; ++kb)
#pragma unroll
                    for (int h = 0; h < 2; ++h) {
                        const int idx = ia[gi][kb][h];
                        if ((unsigned)(idx - lo) < (unsigned)band) {
                            const unsigned* src = (const unsigned*)&xb[idx];
                            const int s = gi * 16 + kb * 4 + h * 2;
                            glds4(src,     &xls[wid][s][0]);      // word 0
                            glds4(src + 1, &xls[wid][s + 1][0]);  // word 1
                        }
                    }
            __builtin_amdgcn_sched_barrier(0);
            if (b < NBANDS - 1) {
                asm volatile("s_waitcnt vmcnt(16)" ::: "memory");
            } else {
                asm volatile("s_waitcnt vmcnt(0)" ::: "memory");
            }
            __builtin_amdgcn_s_barrier();
            __builtin_amdgcn_sched_barrier(0);
        }

        // ---- compute: A-frags from LDS, 16 MFMAs per group ----
#pragma unroll
        for (int gi = 0; gi < NGRP; ++gi) {
            const int gg = p * NGRP + gi;
            if (gg >= ngroups) continue;     // wave-uniform per-group guard
            f32x4 acc[4];
#pragma unroll
            for (int t = 0; t < 4; ++t) acc[t] = (f32x4){0.f, 0.f, 0.f, 0.f};
#pragma unroll
            for (int kb = 0; kb < 4; ++kb) {
                const int s = gi * 16 + kb * 4;
                U4S8 a;
                a.u = make_uint4(xls[wid][s + 0][lane], xls[wid][s + 1][lane],
                                 xls[wid][s + 2][lane], xls[wid][s + 3][lane]);
#pragma unroll
                for (int t = 0; t < 4; ++t)
                    acc[t] = __builtin_amdgcn_mfma_f32_16x16x32_bf16(
                                 a.s, bfrag[t][kb].s, acc[t], 0, 0, 0);
            }

            // C/D: channel = t*16 + (lane&15), node = gbase + grp*4 + j
            const int gbase = gg << 4;
#pragma unroll
            for (int t = 0; t < 4; ++t) {
#pragma unroll
                for (int j = 0; j < 4; ++j) {
                    const int nr = gbase + grp * 4 + j;
                    const float v = acc[t][j];
                    if (nr < n_out) {
                        yb[(size_t)nr * COUT + t * 16 + row] =
                            (unsigned short)f2bf(v);
                        sum[t]   += v;
                        sumsq[t]  = fmaf(v, v, sumsq[t]);
                    }
                }
            }
        }
    }

    // ---- stats reduction; scratch aliases xls (dead now; barrier-separated) --
    __syncthreads();
    float (*redS)[4][16] = (float (*)[4][16])&xls[0][0][0];
    float (*redQ)[4][16] = (float (*)[4][16])&xls[1][0][0];
#pragma unroll
    for (int t = 0; t < 4; ++t) {
        float s = sum[t], q = sumsq[t];
        s += __shfl_xor(s, 16); s += __shfl_xor(s, 32);
        q += __shfl_xor(q, 16); q += __shfl_xor(q, 32);
        if (lane < 16) { redS[wid][t][lane] = s; redQ[wid][t][lane] = q; }
    }
    __syncthreads();
    if (threadIdx.x < 128) {
        const int which = threadIdx.x >> 6;       // 0 = sum, 1 = sumsq
        const int o = threadIdx.x & 63;
        const int t = o >> 4, c = o & 15;
        float tot;
        if (which == 0)
            tot = redS[0][t][c] + redS[1][t][c] + redS[2][t][c] + redS[3][t][c];
        else
            tot = redQ[0][t][c] + redQ[1][t][c] + redQ[2][t][c] + redQ[3][t][c];
        atomicAdd(&stats[which * COUT + o], tot);
    }
}

// ---------------- Kernel 2: finalize BN affine + write depth output ----------------
__global__ void finalize_kernel(
    const float* __restrict__ stats,
    const float* __restrict__ gamma,
    const float* __restrict__ beta,
    float*       __restrict__ scaleshift,  // [128]: scale[64], shift[64]
    const int*   __restrict__ depth,
    float*       __restrict__ out_tail,    // &out[n_pool*64]
    int n_out, int write_depth)
{
    int o = threadIdx.x;
    if (o < COUT) {
        float invn  = 1.0f / (float)n_out;
        float mean  = stats[o] * invn;
        float var   = stats[COUT + o] * invn - mean * mean;  // population var
        float scale = gamma[o] * rsqrtf(var + BN_EPS);
        scaleshift[o]        = scale;
        scaleshift[COUT + o] = beta[o] - mean * scale;
    }
    if (o == 0 && write_depth) {
        out_tail[0] = (float)(depth[0] - 2);
    }
}

// ---------------- Kernel 3: affine + ReLU + max-pool over 8 children ----------------
__global__ __launch_bounds__(256) void pool_kernel(
    const uint2*  __restrict__ yb2,        // y as [N_out][16] packed bf16 quads
    const int*    __restrict__ pidx,       // [N_pool][8]
    const float4* __restrict__ scaleshift4,// [32]: scale4[16], shift4[16]
    float4*       __restrict__ out4,       // [N_pool][16]
    int n_pool)
{
    const int t = blockIdx.x * 256 + threadIdx.x;
    const int q = t & 15;
    const int n = t >> 4;
    if (n >= n_pool) return;

    const float4 sc = scaleshift4[q];
    const float4 sh = scaleshift4[16 + q];

    int idx[8];
#pragma unroll
    for (int j = 0; j < 8; ++j) idx[j] = pidx[n * 8 + j];

    uint2 v[8];
#pragma unroll
    for (int j = 0; j < 8; ++j) v[j] = yb2[(size_t)idx[j] * 16 + q];

    float4 m = make_float4(-INFINITY, -INFINITY, -INFINITY, -INFINITY);
#pragma unroll
    for (int j = 0; j < 8; ++j) {
        float f0 = __uint_as_float(v[j].x << 16);
        float f1 = __uint_as_float(v[j].x & 0xffff0000u);
        float f2 = __uint_as_float(v[j].y << 16);
        float f3 = __uint_as_float(v[j].y & 0xffff0000u);
        m.x = fmaxf(m.x, fmaf(f0, sc.x, sh.x));
        m.y = fmaxf(m.y, fmaf(f1, sc.y, sh.y));
        m.z = fmaxf(m.z, fmaf(f2, sc.z, sh.z));
        m.w = fmaxf(m.w, fmaf(f3, sc.w, sh.w));
    }
    m.x = fmaxf(m.x, 0.f); m.y = fmaxf(m.y, 0.f);
    m.z = fmaxf(m.z, 0.f); m.w = fmaxf(m.w, 0.f);
    out4[(size_t)n * 16 + q] = m;
}

// ---------------- Launch ----------------
extern "C" void kernel_launch(void* const* d_in, const int* in_sizes, int n_in_args,
                              void* d_out, int out_size, void* d_ws, size_t ws_size,
                              hipStream_t stream)
{
    const float4* x     = (const float4*)d_in[0];
    const float*  w     = (const float*) d_in[1];
    const float*  gamma = (const float*) d_in[2];
    const float*  beta  = (const float*) d_in[3];
    const int*    nidx  = (const int*)   d_in[4];
    const int*    pidx  = (const int*)   d_in[5];
    const int*    depth = (const int*)   d_in[6];

    const int n_in   = in_sizes[0] / 4;
    const int n_out  = in_sizes[4] / KNB;
    const int n_pool = in_sizes[5] / 8;
    const int band   = (n_in + NBANDS - 1) / NBANDS;   // ~250k rows = 2MB

    // workspace layout
    float* stats      = (float*)d_ws;                       // 128 f32
    float* scaleshift = (float*)((char*)d_ws + 512);        // 128 f32
    unsigned short* yb = (unsigned short*)((char*)d_ws + 1024);  // n_out*64 bf16
    size_t yb_bytes   = ((size_t)n_out * COUT * 2 + 255) & ~(size_t)255;
    uint2* xb         = (uint2*)((char*)d_ws + 1024 + yb_bytes); // n_in*8 B
    float* out        = (float*)d_out;

    hipMemsetAsync(stats, 0, 2 * COUT * sizeof(float), stream);

    xconv_kernel<<<(n_in + 255) / 256, 256, 0, stream>>>(x, xb, n_in);

    // 3 blocks/CU co-resident (LDS 48KB x 3 = 144KB), single generation
    conv_stats_kernel<<<768, 256, 0, stream>>>(xb, w, nidx, yb, stats,
                                               n_out, band);

    const int write_depth = (out_size > n_pool * COUT) ? 1 : 0;
    finalize_kernel<<<1, 64, 0, stream>>>(stats, gamma, beta, scaleshift,
                                          depth, out + (size_t)n_pool * COUT,
                                          n_out, write_depth);

    const int pool_blocks = (n_pool * 16 + 255) / 256;
    pool_kernel<<<pool_blocks, 256, 0, stream>>>((const uint2*)yb, pidx,
                                                 (const float4*)scaleshift,
                                                 (float4*)out, n_pool);
}

// Round 18
// 145.463 us; speedup vs baseline: 1.0752x; 1.0752x over previous
//
#include <hip/hip_runtime.h>

#define COUT 64
#define KNB 27
#define BN_EPS 1e-5f
#define NBANDS 6
#define NGRP 4   // groups (of 16 nodes) per wave per iteration

typedef __attribute__((ext_vector_type(8))) short short8v;  // 8 bf16 (4 VGPRs)
typedef __attribute__((ext_vector_type(4))) float f32x4;

union U4S8 { uint4 u; short8v s; };

// f32 -> bf16, round-to-nearest-even
static __device__ __forceinline__ unsigned f2bf(float f) {
    unsigned u = __float_as_uint(f);
    return (u + 0x7fffu + ((u >> 16) & 1u)) >> 16;
}

// scattered gather direct to LDS: per-lane global src, dest = lbase + lane*4
static __device__ __forceinline__ void glds4(const void* g, void* l) {
    __builtin_amdgcn_global_load_lds(
        (const __attribute__((address_space(1))) void*)g,
        (__attribute__((address_space(3))) void*)l, 4, 0, 0);
}

// ---------------- Kernel 0: pre-convert x rows to packed bf16 ----------------
__global__ __launch_bounds__(256) void xconv_kernel(
    const float4* __restrict__ x, uint2* __restrict__ xb, int n_in)
{
    int i = blockIdx.x * 256 + threadIdx.x;
    if (i >= n_in) return;
    float4 r = x[i];
    uint2 o;
    o.x = f2bf(r.x) | (f2bf(r.y) << 16);
    o.y = f2bf(r.z) | (f2bf(r.w) << 16);
    xb[i] = o;
}

// ---------------- Kernel 1: banded gather-conv, gathers DMA'd to LDS ----------
// FINAL (= R16, best measured: conv ~120.5us, total ~145.5us).
// Structure distilled over R4-R17:
//  - MFMA formulation: wave owns 16-node groups; A = gathered rows as bf16,
//    B = weights in LDS; per-lane scattered gathers (not wave-uniform).
//  - Gathers DMA directly to LDS via global_load_lds: zero dest VGPRs, no
//    WAW chains (the register file was the serializer in R5/R8/R9/R10).
//  - 6-band temporal sweep of the 12MB x footprint with counted vmcnt(32)
//    drains + s_barrier pacing: L2 holds ~1 band/XCD -> FETCH ~259MB (the
//    LDS-capacity-bound floor of ~2.25 sweeps + nidx).
//  - NGRP=4 (64 nodes/wave/sweep), 80KB LDS, 2 blocks/CU.
// Explored and rejected: unbanded max-MLP (3.8 TB/s scattered-line ceiling,
// 650MB), no-drain issue-order banding (locality collapses), NT hints on
// sub-line stores (partial-sector writes+RMW), 3-block corners (traffic and
// BW move together -> time invariant ~120-135us). This is the plateau.
__global__ __launch_bounds__(256, 2) void conv_stats_kernel(
    const uint2* __restrict__ xb,      // [N_in] packed bf16 rows (8B)
    const float* __restrict__ w,       // [27][4][64]
    const int*   __restrict__ nidx,    // [N_out][27]
    unsigned short* __restrict__ yb,   // [N_out][64] bf16 (workspace)
    float*       __restrict__ stats,   // [128]: sum[64], sumsq[64]
    int n_out, int band)
{
    const int lane = threadIdx.x & 63;
    const int wid  = threadIdx.x >> 6;
    const int row  = lane & 15;   // A-row (node) / B-col (channel) selector
    const int grp  = lane >> 4;   // k-chunk selector
    const int gwave   = blockIdx.x * 4 + wid;
    const int nwaves  = gridDim.x * 4;
    const int ngroups = (n_out + 15) >> 4;
    const int npairs  = (ngroups + NGRP - 1) / NGRP;
    const int niter   = (npairs + nwaves - 1) / nwaves;   // uniform trip count

    // ---- B fragments in LDS (16KB) ----
    __shared__ uint4 blds[16 * 64];
    // ---- per-wave gather buffer: [wave][slot][lane] uint, slot = gi*16+kb*4+h*2+w
    __shared__ unsigned xls[4][NGRP * 16][64];   // 64KB

#pragma unroll
    for (int pp = 0; pp < 4; ++pp) {
        const int pair = wid * 4 + pp;        // pair = kb*4 + t
        const int kb = pair >> 2, t = pair & 3;
        const int o = t * 16 + row;
        unsigned e[8];
#pragma unroll
        for (int j = 0; j < 8; ++j) {
            const int k = kb * 32 + grp * 8 + j;
            float v = (k < KNB * 4) ? w[k * COUT + o] : 0.0f;
            e[j] = f2bf(v);
        }
        uint4 f;
        f.x = e[0] | (e[1] << 16);
        f.y = e[2] | (e[3] << 16);
        f.z = e[4] | (e[5] << 16);
        f.w = e[6] | (e[7] << 16);
        blds[pair * 64 + lane] = f;
    }
    // zero gather buffer once: always-invalid slots (nb>=27) stay 0 forever;
    // valid slots are overwritten by DMA every iteration.
#pragma unroll
    for (int s = 0; s < NGRP * 16; ++s) xls[wid][s][lane] = 0u;
    __syncthreads();

    float sum[4]   = {0.f, 0.f, 0.f, 0.f};
    float sumsq[4] = {0.f, 0.f, 0.f, 0.f};

    auto load_ia = [&](int pp, int (&ia)[NGRP][4][2]) {
#pragma unroll
        for (int gi = 0; gi < NGRP; ++gi) {
            const int gg = pp * NGRP + gi;
            const int nodeg = (gg << 4) + row;
            const bool vn = (gg < ngroups) && (nodeg < n_out);
#pragma unroll
            for (int kb = 0; kb < 4; ++kb)
#pragma unroll
                for (int h = 0; h < 2; ++h) {
                    const int nb = kb * 8 + grp * 2 + h;
                    ia[gi][kb][h] = (vn && nb < KNB) ? nidx[nodeg * KNB + nb] : -1;
                }
        }
    };

    int ia_cur[NGRP][4][2];
    load_ia(gwave, ia_cur);

    for (int it = 0; it < niter; ++it) {
        const int p = gwave + it * nwaves;   // may exceed npairs (all ia = -1)

        int ia_nxt[NGRP][4][2];

        // ---- banded gather sweep: DMA to LDS, counted drains ----
#pragma unroll
        for (int b = 0; b < NBANDS; ++b) {
            const int lo = b * band;
#pragma unroll
            for (int gi = 0; gi < NGRP; ++gi)
#pragma unroll
                for (int kb = 0; kb < 4; ++kb)
#pragma unroll
                    for (int h = 0; h < 2; ++h) {
                        const int idx = ia_cur[gi][kb][h];
                        if ((unsigned)(idx - lo) < (unsigned)band) {
                            const unsigned* src = (const unsigned*)&xb[idx];
                            const int s = gi * 16 + kb * 4 + h * 2;
                            glds4(src,     &xls[wid][s][0]);      // word 0
                            glds4(src + 1, &xls[wid][s + 1][0]);  // word 1
                        }
                    }
            if (b == 0) load_ia(p + nwaves, ia_nxt);  // prefetch during band 0
            __builtin_amdgcn_sched_barrier(0);
            if (b < NBANDS - 1) {
                // bounded overlap: <=32 gathers stay in flight across boundary
                asm volatile("s_waitcnt vmcnt(32)" ::: "memory");
            } else {
                // final band: buffer must be fully landed before ds_reads
                asm volatile("s_waitcnt vmcnt(0)" ::: "memory");
            }
            __builtin_amdgcn_s_barrier();
            __builtin_amdgcn_sched_barrier(0);
        }

        // ---- compute: A-frags from LDS, 16 MFMAs per group ----
        if (p < npairs) {
#pragma unroll
            for (int gi = 0; gi < NGRP; ++gi) {
                f32x4 acc[4];
#pragma unroll
                for (int t = 0; t < 4; ++t) acc[t] = (f32x4){0.f, 0.f, 0.f, 0.f};
#pragma unroll
                for (int kb = 0; kb < 4; ++kb) {
                    const int s = gi * 16 + kb * 4;
                    U4S8 a;
                    a.u = make_uint4(xls[wid][s + 0][lane], xls[wid][s + 1][lane],
                                     xls[wid][s + 2][lane], xls[wid][s + 3][lane]);
#pragma unroll
                    for (int t = 0; t < 4; ++t) {
                        U4S8 bb;
                        bb.u = blds[(kb * 4 + t) * 64 + lane];
                        acc[t] = __builtin_amdgcn_mfma_f32_16x16x32_bf16(
                                     a.s, bb.s, acc[t], 0, 0, 0);
                    }
                }

                // C/D: channel = t*16 + (lane&15), node = gbase + grp*4 + j
                const int gbase = (p * NGRP + gi) << 4;
#pragma unroll
                for (int t = 0; t < 4; ++t) {
#pragma unroll
                    for (int j = 0; j < 4; ++j) {
                        const int nr = gbase + grp * 4 + j;
                        const float v = acc[t][j];
                        if (nr < n_out)
                            yb[(size_t)nr * COUT + t * 16 + row] =
                                (unsigned short)f2bf(v);
                        sum[t]   += v;         // padded rows contribute exact 0
                        sumsq[t]  = fmaf(v, v, sumsq[t]);
                    }
                }
            }
        }

#pragma unroll
        for (int gi = 0; gi < NGRP; ++gi)
#pragma unroll
            for (int kb = 0; kb < 4; ++kb)
#pragma unroll
                for (int h = 0; h < 2; ++h)
                    ia_cur[gi][kb][h] = ia_nxt[gi][kb][h];
    }

    // ---- stats reduction; scratch aliases xls (dead now; barrier-separated) --
    __syncthreads();
    float (*redS)[4][16] = (float (*)[4][16])&xls[0][0][0];
    float (*redQ)[4][16] = (float (*)[4][16])&xls[1][0][0];
#pragma unroll
    for (int t = 0; t < 4; ++t) {
        float s = sum[t], q = sumsq[t];
        s += __shfl_xor(s, 16); s += __shfl_xor(s, 32);
        q += __shfl_xor(q, 16); q += __shfl_xor(q, 32);
        if (lane < 16) { redS[wid][t][lane] = s; redQ[wid][t][lane] = q; }
    }
    __syncthreads();
    if (threadIdx.x < 128) {
        const int which = threadIdx.x >> 6;       // 0 = sum, 1 = sumsq
        const int o = threadIdx.x & 63;
        const int t = o >> 4, c = o & 15;
        float tot;
        if (which == 0)
            tot = redS[0][t][c] + redS[1][t][c] + redS[2][t][c] + redS[3][t][c];
        else
            tot = redQ[0][t][c] + redQ[1][t][c] + redQ[2][t][c] + redQ[3][t][c];
        atomicAdd(&stats[which * COUT + o], tot);
    }
}

// ---------------- Kernel 2: finalize BN affine + write depth output ----------------
__global__ void finalize_kernel(
    const float* __restrict__ stats,
    const float* __restrict__ gamma,
    const float* __restrict__ beta,
    float*       __restrict__ scaleshift,  // [128]: scale[64], shift[64]
    const int*   __restrict__ depth,
    float*       __restrict__ out_tail,    // &out[n_pool*64]
    int n_out, int write_depth)
{
    int o = threadIdx.x;
    if (o < COUT) {
        float invn  = 1.0f / (float)n_out;
        float mean  = stats[o] * invn;
        float var   = stats[COUT + o] * invn - mean * mean;  // population var
        float scale = gamma[o] * rsqrtf(var + BN_EPS);
        scaleshift[o]        = scale;
        scaleshift[COUT + o] = beta[o] - mean * scale;
    }
    if (o == 0 && write_depth) {
        out_tail[0] = (float)(depth[0] - 2);
    }
}

// ---------------- Kernel 3: affine + ReLU + max-pool over 8 children ----------------
__global__ __launch_bounds__(256) void pool_kernel(
    const uint2*  __restrict__ yb2,        // y as [N_out][16] packed bf16 quads
    const int*    __restrict__ pidx,       // [N_pool][8]
    const float4* __restrict__ scaleshift4,// [32]: scale4[16], shift4[16]
    float4*       __restrict__ out4,       // [N_pool][16]
    int n_pool)
{
    const int t = blockIdx.x * 256 + threadIdx.x;
    const int q = t & 15;
    const int n = t >> 4;
    if (n >= n_pool) return;

    const float4 sc = scaleshift4[q];
    const float4 sh = scaleshift4[16 + q];

    int idx[8];
#pragma unroll
    for (int j = 0; j < 8; ++j) idx[j] = pidx[n * 8 + j];

    uint2 v[8];
#pragma unroll
    for (int j = 0; j < 8; ++j) v[j] = yb2[(size_t)idx[j] * 16 + q];

    float4 m = make_float4(-INFINITY, -INFINITY, -INFINITY, -INFINITY);
#pragma unroll
    for (int j = 0; j < 8; ++j) {
        float f0 = __uint_as_float(v[j].x << 16);
        float f1 = __uint_as_float(v[j].x & 0xffff0000u);
        float f2 = __uint_as_float(v[j].y << 16);
        float f3 = __uint_as_float(v[j].y & 0xffff0000u);
        m.x = fmaxf(m.x, fmaf(f0, sc.x, sh.x));
        m.y = fmaxf(m.y, fmaf(f1, sc.y, sh.y));
        m.z = fmaxf(m.z, fmaf(f2, sc.z, sh.z));
        m.w = fmaxf(m.w, fmaf(f3, sc.w, sh.w));
    }
    m.x = fmaxf(m.x, 0.f); m.y = fmaxf(m.y, 0.f);
    m.z = fmaxf(m.z, 0.f); m.w = fmaxf(m.w, 0.f);
    out4[(size_t)n * 16 + q] = m;
}

// ---------------- Launch ----------------
extern "C" void kernel_launch(void* const* d_in, const int* in_sizes, int n_in_args,
                              void* d_out, int out_size, void* d_ws, size_t ws_size,
                              hipStream_t stream)
{
    const float4* x     = (const float4*)d_in[0];
    const float*  w     = (const float*) d_in[1];
    const float*  gamma = (const float*) d_in[2];
    const float*  beta  = (const float*) d_in[3];
    const int*    nidx  = (const int*)   d_in[4];
    const int*    pidx  = (const int*)   d_in[5];
    const int*    depth = (const int*)   d_in[6];

    const int n_in   = in_sizes[0] / 4;
    const int n_out  = in_sizes[4] / KNB;
    const int n_pool = in_sizes[5] / 8;
    const int band   = (n_in + NBANDS - 1) / NBANDS;   // ~250k rows = 2MB

    // workspace layout
    float* stats      = (float*)d_ws;                       // 128 f32
    float* scaleshift = (float*)((char*)d_ws + 512);        // 128 f32
    unsigned short* yb = (unsigned short*)((char*)d_ws + 1024);  // n_out*64 bf16
    size_t yb_bytes   = ((size_t)n_out * COUT * 2 + 255) & ~(size_t)255;
    uint2* xb         = (uint2*)((char*)d_ws + 1024 + yb_bytes); // n_in*8 B
    float* out        = (float*)d_out;

    hipMemsetAsync(stats, 0, 2 * COUT * sizeof(float), stream);

    xconv_kernel<<<(n_in + 255) / 256, 256, 0, stream>>>(x, xb, n_in);

    // 2 blocks/CU co-resident (LDS 80KB x 2 = 160KB), single generation
    conv_stats_kernel<<<512, 256, 0, stream>>>(xb, w, nidx, yb, stats,
                                               n_out, band);

    const int write_depth = (out_size > n_pool * COUT) ? 1 : 0;
    finalize_kernel<<<1, 64, 0, stream>>>(stats, gamma, beta, scaleshift,
                                          depth, out + (size_t)n_pool * COUT,
                                          n_out, write_depth);

    const int pool_blocks = (n_pool * 16 + 255) / 256;
    pool_kernel<<<pool_blocks, 256, 0, stream>>>((const uint2*)yb, pidx,
                                                 (const float4*)scaleshift,
                                                 (float4*)out, n_pool);
}